// Round 6
// baseline (42714.203 us; speedup 1.0000x reference)
//
#include <hip/hip_runtime.h>
#include <math.h>

// ---------------------------------------------------------------------------
// 2-layer bidirectional LSTM, variational dropout, fp32 — persistent kernels.
// Round 6: break the LDS-read-throughput bound of round 5 (32 ds_read_b128
// per chunk per wave ≈ 1536 LDS-cyc vs 512 VALU-cyc -> 24% VALUBusy).
//   * W is pre-transposed ONCE into WT[cell][k][2048] (ws) and read straight
//     from global/L2 in the inner loop (f32x4, 16-lane broadcast) — W leaves
//     LDS entirely (removes half the LDS reads + all swizzled Wt writes).
//   * per-lane tile 4b x 8c (acc[4][8]); 16 r-groups x 2 c-groups x 2 k-halves
//     = 64 lanes; k-halves reduced with one __shfl_xor(,32).
//   * 512-thread WGs (8 waves, 2/SIMD) for latency hiding; LDS = 34.8 KB.
// Coherence (proven round 5, kept identical): fence-free relaxed agent-scope
// grid barrier; h through fabric via sc0 sc1 stores/loads; hmT parity
// double-buffer kills the WAR race; weights/x/masks stay L2-resident.
// ---------------------------------------------------------------------------

typedef float f32x4 __attribute__((ext_vector_type(4)));

#define SLEN   512
#define HID    512
#define CHK    64
#define APAD   68                         // padded LDS row stride (floats)
#define OUT_SEQ  (SLEN*64*2*HID)          // 33,554,432 floats
#define STATE_SZ (4*64*HID)               // 131,072 floats (one h buffer)
#define WT_ROWS  5120                     // 2*1024 (L0 cells) + 2*1536 (L1)

__global__ __launch_bounds__(256) void init_ws(float* __restrict__ hmT,
                                               unsigned* __restrict__ bar) {
    const int b = blockIdx.x, t = threadIdx.x;
    if (b < 128) {                         // zero h buffer 0 (h0 = 0)
        *(f32x4*)(hmT + (b*256 + t)*4) = (f32x4){0.f, 0.f, 0.f, 0.f};
    } else {                               // zero barrier block (2048 u32)
        bar[(b - 128)*256 + t] = 0u;
    }
}

// WT[cell] row r (k-index, ih rows then hh rows) x 2048 gate-cols.
// Tiled 64x64 transpose, coalesced read + coalesced write via LDS.
__global__ __launch_bounds__(256) void transpose_w(
    const float* __restrict__ Wih0,   // [2,2048,512]
    const float* __restrict__ Wih1,   // [2,2048,1024]
    const float* __restrict__ Whh,    // [4,2048,512]
    float* __restrict__ WT)           // [5120, 2048]
{
    int id = blockIdx.x;               // 0..2559
    int cell, rem;
    if (id < 1024) { cell = id >> 9;            rem = id & 511; }  // 16x32 tiles
    else { id -= 1024; cell = 2 + (id >= 768);  rem = id % 768; }  // 24x32 tiles
    const int ktile = rem >> 5, gtile = rem & 31;
    const int k0 = ktile*64, g0 = gtile*64;
    const int Kin = (cell < 2) ? 512 : 1024;

    const float* src; int ks; size_t srow;
    if (k0 < Kin) {
        src = (cell < 2) ? Wih0 + (size_t)cell*2048*512
                         : Wih1 + (size_t)(cell-2)*2048*1024;
        ks = k0; srow = Kin;
    } else {
        src = Whh + (size_t)cell*2048*512;
        ks = k0 - Kin; srow = 512;
    }

    __shared__ float T[64][65];
    const int tid = threadIdx.x;
    {   // load: rows g0+i, 16 contiguous k per thread
        const int i = tid >> 2, j0 = (tid & 3)*16;
        const float* p = src + (size_t)(g0 + i)*srow + ks + j0;
#pragma unroll
        for (int q = 0; q < 4; ++q)
            *(f32x4*)(&T[i][j0 + q*4]) = *(const f32x4*)(p + q*4);
    }
    __syncthreads();
    {   // store: rows k0+j, 64 contiguous g per wave
        const size_t rowOff = (cell == 0) ? 0 : (cell == 1) ? 1024
                            : (cell == 2) ? 2048 : 3584;
        const int jj0 = (tid >> 6)*16, ii = tid & 63;
#pragma unroll
        for (int jj = 0; jj < 16; ++jj)
            WT[(rowOff + k0 + jj0 + jj)*2048 + g0 + ii] = T[ii][jj0 + jj];
    }
}

// Grid barrier, fence-free (relaxed agent-scope fabric atomics only).
// bar (u32): leaf[l] at l*16 (l=0..31), root at 512, generation at 513.
__device__ __forceinline__ void bar_arrive(unsigned* bar, int g) {
    __syncthreads();                  // drain all waves' h-stores (vmcnt(0))
    if (threadIdx.x == 0) {
        unsigned lo = __hip_atomic_fetch_add(bar + (g & 31)*16, 1u,
                          __ATOMIC_RELAXED, __HIP_MEMORY_SCOPE_AGENT);
        if (lo == 7u) {
            unsigned ro = __hip_atomic_fetch_add(bar + 512, 1u,
                              __ATOMIC_RELAXED, __HIP_MEMORY_SCOPE_AGENT);
            if (ro == 31u) {
                for (int i = 0; i < 32; ++i)
                    __hip_atomic_store(bar + i*16, 0u,
                        __ATOMIC_RELAXED, __HIP_MEMORY_SCOPE_AGENT);
                __hip_atomic_store(bar + 512, 0u,
                    __ATOMIC_RELAXED, __HIP_MEMORY_SCOPE_AGENT);
                asm volatile("s_waitcnt vmcnt(0)" ::: "memory");
                __hip_atomic_fetch_add(bar + 513, 1u,
                    __ATOMIC_RELAXED, __HIP_MEMORY_SCOPE_AGENT);
            }
        }
    }
}

__device__ __forceinline__ void bar_wait(unsigned* bar, unsigned s) {
    if (threadIdx.x == 0) {
        while (__hip_atomic_load(bar + 513, __ATOMIC_RELAXED,
                                 __HIP_MEMORY_SCOPE_AGENT) < s)
            __builtin_amdgcn_s_sleep(1);
    }
    __syncthreads();
}

template<int LAYER>
__global__ __launch_bounds__(512, 2) void lstm_layer(
    const float* __restrict__ x,      // [512,64,512]
    const float* __restrict__ WT,     // ws: [5120,2048] transposed weights
    const float* __restrict__ bih,    // [4,2048]
    const float* __restrict__ bhh,    // [4,2048]
    const float* __restrict__ mx0,    // [2,64,512]
    const float* __restrict__ mx1,    // [2,64,1024]
    const float* __restrict__ mhm,    // [4,64,512]
    float* __restrict__ out0,         // ws: [512,64,1024] layer-0 output
    float* __restrict__ hmT,          // ws: [2][4,512,64] (h*mh)^T dbl-buffered
    unsigned* __restrict__ barbase,   // ws: barrier block
    float* __restrict__ dout)         // [S,B,1024] ++ hn[4,64,512] ++ cn[4,64,512]
{
    constexpr int Kin = LAYER ? 1024 : 512;
    constexpr int NCH = (Kin + HID)/CHK;       // 16 (L0) or 24 (L1)
    constexpr int HCH = Kin/CHK;               // first h chunk: 8 / 16

    __shared__ __align__(16) float At[2][CHK*APAD];   // 2 x 17.4 KB

    unsigned* bar = barbase + LAYER*1024;

    const int g    = blockIdx.x;
    const int dir  = g >> 7;
    const int wg   = g & 127;
    const int cell = LAYER*2 + dir;
    const int u0   = wg*4;
    const int tid  = threadIdx.x;
    const int lane = tid & 63;
    const int wv   = tid >> 6;                 // wave 0..7

    // compute tile: 4 batch x 8 cols per lane; 2 k-halves within the wave
    const int r0    = (lane & 15)*4;           // batch rows r0..r0+3
    const int cq    = (lane >> 4) & 1;         // col-group: local cols cq*8..+8
    const int c0    = cq*8;
    const int kbase = wv*8 + (lane >> 5)*4;    // this lane's 4 k-rows in chunk
    const int wcb   = cq*1024 + u0;            // WT col offset (2 gate quads)
    const size_t rowOff = LAYER ? (2048 + (size_t)dir*1536) : ((size_t)dir*1024);
    const float* WTc = WT + rowOff*2048;

    // x staging: thread -> (batch sb, k-octet aks)
    const int sb  = tid & 63;
    const int aks = (tid >> 6)*8;
    // h staging: thread -> (k-row hkrow, batch-octet hb)
    const int hkrow = tid >> 3;
    const int hb    = (tid & 7)*8;

    // elementwise (first 256 threads): (batch eb, unit u0+eu)
    const int eb = tid & 63;
    const int eu = tid >> 6;
    float bsum[4] = {0.f, 0.f, 0.f, 0.f};
    float mreg = 0.f;
    float* haddr0 = nullptr;
    size_t sidx = 0;
    if (tid < 256) {
#pragma unroll
        for (int q = 0; q < 4; ++q) {
            const int gc = cell*2048 + q*512 + u0 + eu;
            bsum[q] = bih[gc] + bhh[gc];
        }
        sidx  = ((size_t)(cell*64 + eb))*512 + u0 + eu;
        mreg  = mhm[sidx];
        haddr0 = hmT + ((size_t)(cell*512 + u0 + eu))*64 + eb;
    }
    float creg = 0.0f;

    for (int s = 0; s < SLEN; ++s) {
        const int t = dir ? (SLEN-1-s) : s;
        const float* hrd = hmT + (size_t)(s & 1)*STATE_SZ;
        float* const hwr = haddr0 + (size_t)((s + 1) & 1)*STATE_SZ;

        float acc[4][8];
#pragma unroll
        for (int i = 0; i < 4; ++i)
#pragma unroll
            for (int j = 0; j < 8; ++j) acc[i][j] = 0.0f;

        f32x4 va0, va1, vm0, vm1;
        bool xpart = true;

        auto prefetch = [&](int ch) {
            const int k0 = ch*CHK;
            xpart = (k0 < Kin);
            if (xpart) {
                const float *asrc, *amsk;
                if (LAYER == 0) {
                    asrc = x   + ((size_t)(t*64   + sb))*512  + k0 + aks;
                    amsk = mx0 + ((size_t)(dir*64 + sb))*512  + k0 + aks;
                } else {
                    asrc = out0 + ((size_t)(t*64   + sb))*1024 + k0 + aks;
                    amsk = mx1  + ((size_t)(dir*64 + sb))*1024 + k0 + aks;
                }
                va0 = *(const f32x4*)(asrc);     vm0 = *(const f32x4*)(amsk);
                va1 = *(const f32x4*)(asrc + 4); vm1 = *(const f32x4*)(amsk + 4);
            } else {
                const int kh = k0 - Kin;
                const float* hsrc = hrd + ((size_t)(cell*512 + kh + hkrow))*64 + hb;
                asm volatile("global_load_dwordx4 %0, %1, off sc0 sc1 nt"
                             : "=v"(va0) : "v"(hsrc)     : "memory");
                asm volatile("global_load_dwordx4 %0, %1, off sc0 sc1 nt"
                             : "=v"(va1) : "v"(hsrc + 4) : "memory");
            }
        };

        auto writeb = [&](float* Ab) {
            if (xpart) {
                const f32x4 p0 = va0*vm0, p1 = va1*vm1;
                float* col = Ab + aks*APAD + sb;
                col[0*APAD] = p0.x; col[1*APAD] = p0.y;
                col[2*APAD] = p0.z; col[3*APAD] = p0.w;
                col[4*APAD] = p1.x; col[5*APAD] = p1.y;
                col[6*APAD] = p1.z; col[7*APAD] = p1.w;
            } else {
                asm volatile("s_waitcnt vmcnt(0)" ::: "memory");
                *(f32x4*)(Ab + hkrow*APAD + hb)     = va0;
                *(f32x4*)(Ab + hkrow*APAD + hb + 4) = va1;
            }
        };

        auto compute = [&](const float* Ab, int k0) {
#pragma unroll
            for (int kk = 0; kk < 4; ++kk) {
                const int krow = kbase + kk;
                const f32x4 a  = *(const f32x4*)(Ab + krow*APAD + r0);
                const float* wr = WTc + (size_t)(k0 + krow)*2048 + wcb;
                const f32x4 w0 = *(const f32x4*)(wr);
                const f32x4 w1 = *(const f32x4*)(wr + 512);
#pragma unroll
                for (int i = 0; i < 4; ++i) {
                    acc[i][0] += a[i]*w0.x; acc[i][1] += a[i]*w0.y;
                    acc[i][2] += a[i]*w0.z; acc[i][3] += a[i]*w0.w;
                    acc[i][4] += a[i]*w1.x; acc[i][5] += a[i]*w1.y;
                    acc[i][6] += a[i]*w1.z; acc[i][7] += a[i]*w1.w;
                }
            }
        };

        // ---- pipelined K loop: sync -> [wait] -> prefetch(next) -> compute ----
        prefetch(0);
        writeb(At[0]);
        for (int ch = 0; ch < NCH; ++ch) {
            __syncthreads();
            if (ch == HCH - 1 && s > 0)
                bar_wait(bar, (unsigned)s);      // h(s) fabric-visible
            const int p = ch & 1;
            if (ch + 1 < NCH) prefetch(ch + 1);
            compute(At[p], ch*CHK);
            if (ch + 1 < NCH) writeb(At[p^1]);
        }

        // ---- reduce: k-halves via shuffle, then 8 waves via LDS ----
#pragma unroll
        for (int i = 0; i < 4; ++i)
#pragma unroll
            for (int j = 0; j < 8; ++j)
                acc[i][j] += __shfl_xor(acc[i][j], 32);
        float* red = At[0];
        if (lane < 32) {
#pragma unroll
            for (int j = 0; j < 8; ++j) {
                f32x4 v = {acc[0][j], acc[1][j], acc[2][j], acc[3][j]};
                *(f32x4*)(red + wv*1024 + (c0 + j)*64 + r0) = v;
            }
        }
        __syncthreads();

        // ---- elementwise + state update (first 256 threads) ----
        if (tid < 256) {
            float gq[4];
#pragma unroll
            for (int q = 0; q < 4; ++q) {
                const int c = q*4 + eu;
                float v = bsum[q];
#pragma unroll
                for (int w = 0; w < 8; ++w) v += red[w*1024 + c*64 + eb];
                gq[q] = v;
            }
            const float ig = 1.0f/(1.0f + expf(-gq[0]));
            const float fg = 1.0f/(1.0f + expf(-gq[1]));
            const float gg = tanhf(gq[2]);
            const float og = 1.0f/(1.0f + expf(-gq[3]));
            const float cnew = fg*creg + ig*gg;
            const float hnew = og*tanhf(cnew);
            creg = cnew;
            const float hm = hnew * mreg;
            asm volatile("global_store_dword %0, %1, off sc0 sc1 nt"
                         :: "v"(hwr), "v"(hm) : "memory");
            float* obase = LAYER ? dout : out0;
            obase[((size_t)(t*64 + eb))*1024 + dir*512 + u0 + eu] = hnew;
            if (s == SLEN-1) {
                dout[OUT_SEQ + sidx]            = hnew;   // h_n
                dout[OUT_SEQ + STATE_SZ + sidx] = cnew;   // c_n
            }
        }

        if (s + 1 < SLEN) bar_arrive(bar, g);    // non-blocking arrival
    }
}

extern "C" void kernel_launch(void* const* d_in, const int* in_sizes, int n_in,
                              void* d_out, int out_size, void* d_ws, size_t ws_size,
                              hipStream_t stream)
{
    const float* x    = (const float*)d_in[0];
    const float* Wih0 = (const float*)d_in[1];
    const float* Wih1 = (const float*)d_in[2];
    const float* Whh  = (const float*)d_in[3];
    const float* bih  = (const float*)d_in[4];
    const float* bhh  = (const float*)d_in[5];
    const float* mx0  = (const float*)d_in[6];
    const float* mx1  = (const float*)d_in[7];
    const float* mhm  = (const float*)d_in[8];

    float* out  = (float*)d_out;
    float* out0 = (float*)d_ws;                      // [512,64,1024]
    float* hmT  = out0 + OUT_SEQ;                    // [2][4,512,64]
    float* WT   = hmT + 2*STATE_SZ;                  // [5120,2048]
    unsigned* bar = (unsigned*)(WT + (size_t)WT_ROWS*2048);  // 2 x 1024 u32

    transpose_w<<<2560, 256, 0, stream>>>(Wih0, Wih1, Whh, WT);
    init_ws<<<136, 256, 0, stream>>>(hmT, bar);
    lstm_layer<0><<<256, 512, 0, stream>>>(x, WT, bih, bhh,
                                           mx0, mx1, mhm, out0, hmT, bar, out);
    lstm_layer<1><<<256, 512, 0, stream>>>(x, WT, bih, bhh,
                                           mx0, mx1, mhm, out0, hmT, bar, out);
}

// Round 7
// 35294.629 us; speedup vs baseline: 1.2102x; 1.2102x over previous
//
#include <hip/hip_runtime.h>
#include <math.h>

// ---------------------------------------------------------------------------
// 2-layer bidirectional LSTM, variational dropout, fp32 — persistent kernels.
// Round 7: fix round 6's HBM weight-streaming (FETCH 107 MB/step = 4x line
// over-fetch: each lane used 16 B of every 64-B WT line).
//   * Weights packed per-WG: pack[cell][wg][k][16] — the WG's 16 gate-cols
//     contiguous per k-row (dense 64-B rows). Per-XCD footprint 3.1 MB ->
//     L2-resident across all 512 steps.
//   * Tile remap: 16 b-groups x 4 c-groups (acc[4][4]); each wave owns 8
//     k-rows/chunk -> A-read is single-row broadcast ds_read_b128
//     (conflict-free); W = one dense f32x4/lane from L2, preloaded 8-deep.
//   * __syncthreads() before reduce-buffer write (closes r6 latent race).
// Coherence (proven r5/r6): fence-free relaxed agent-scope grid barrier;
// h via sc0 sc1 fabric stores/loads; hmT parity double-buffer; c in register.
// ---------------------------------------------------------------------------

typedef float f32x4 __attribute__((ext_vector_type(4)));

#define SLEN   512
#define HID    512
#define CHK    64
#define APAD   68                          // LDS row stride (floats)
#define ABUF   (CHK*APAD)                  // 4352 floats per A buffer
#define RPAD   66                          // reduce-buffer row stride
#define OUT_SEQ  (SLEN*64*2*HID)           // 33,554,432 floats
#define STATE_SZ (4*64*HID)                // 131,072 floats (one h buffer)
#define PACK_B2  (2*128*16384)             // float offset of L1 packs
#define PACK_TOTAL (PACK_B2 + 2*128*24576) // 10,485,760 floats (41.9 MB)

__global__ __launch_bounds__(256) void init_ws(float* __restrict__ hmT,
                                               unsigned* __restrict__ bar) {
    const int b = blockIdx.x, t = threadIdx.x;
    if (b < 128) {                         // zero h buffer 0 (h0 = 0)
        *(f32x4*)(hmT + (b*256 + t)*4) = (f32x4){0.f, 0.f, 0.f, 0.f};
    } else {                               // zero barrier block (2048 u32)
        bar[(b - 128)*256 + t] = 0u;
    }
}

// pack[cell][wg][k][16]: c16 = q*4+j  ->  W_cat row q*512 + wg*4 + j, col k
// (k = ih rows 0..Kin-1, then hh rows Kin..Kin+511).
__global__ __launch_bounds__(256) void pack_w(
    const float* __restrict__ Wih0,   // [2,2048,512]
    const float* __restrict__ Wih1,   // [2,2048,1024]
    const float* __restrict__ Whh,    // [4,2048,512]
    float* __restrict__ P)
{
    const int id = blockIdx.x;        // 0..511
    int cell, wg;
    if (id < 256) { cell = id >> 7;              wg = id & 127; }
    else          { cell = 2 + ((id-256) >> 7);  wg = (id-256) & 127; }
    const int Kin  = (cell < 2) ? 512 : 1024;
    const int Ktot = Kin + 512;
    float* dst = (cell < 2)
        ? P + (size_t)(cell*128 + wg)*16384
        : P + (size_t)PACK_B2 + (size_t)((cell-2)*128 + wg)*24576;

    const int c  = threadIdx.x & 15;
    const int kq = threadIdx.x >> 4;       // 0..15
    const int gc = (c >> 2)*512 + wg*4 + (c & 3);

    for (int kb = 0; kb < Ktot; kb += 16) {
        const int k = kb + kq;
        float v;
        if (k < Kin) {
            v = (cell < 2) ? Wih0[((size_t)cell*2048 + gc)*512  + k]
                           : Wih1[((size_t)(cell-2)*2048 + gc)*1024 + k];
        } else {
            v = Whh[((size_t)cell*2048 + gc)*512 + (k - Kin)];
        }
        dst[(size_t)k*16 + c] = v;         // contiguous 256-float block/iter
    }
}

// Grid barrier, fence-free (relaxed agent-scope fabric atomics only).
// bar (u32): leaf[l] at l*16 (l=0..31), root at 512, generation at 513.
__device__ __forceinline__ void bar_arrive(unsigned* bar, int g) {
    __syncthreads();                  // drain all waves' h-stores (vmcnt(0))
    if (threadIdx.x == 0) {
        unsigned lo = __hip_atomic_fetch_add(bar + (g & 31)*16, 1u,
                          __ATOMIC_RELAXED, __HIP_MEMORY_SCOPE_AGENT);
        if (lo == 7u) {
            unsigned ro = __hip_atomic_fetch_add(bar + 512, 1u,
                              __ATOMIC_RELAXED, __HIP_MEMORY_SCOPE_AGENT);
            if (ro == 31u) {
                for (int i = 0; i < 32; ++i)
                    __hip_atomic_store(bar + i*16, 0u,
                        __ATOMIC_RELAXED, __HIP_MEMORY_SCOPE_AGENT);
                __hip_atomic_store(bar + 512, 0u,
                    __ATOMIC_RELAXED, __HIP_MEMORY_SCOPE_AGENT);
                asm volatile("s_waitcnt vmcnt(0)" ::: "memory");
                __hip_atomic_fetch_add(bar + 513, 1u,
                    __ATOMIC_RELAXED, __HIP_MEMORY_SCOPE_AGENT);
            }
        }
    }
}

__device__ __forceinline__ void bar_wait(unsigned* bar, unsigned s) {
    if (threadIdx.x == 0) {
        while (__hip_atomic_load(bar + 513, __ATOMIC_RELAXED,
                                 __HIP_MEMORY_SCOPE_AGENT) < s)
            __builtin_amdgcn_s_sleep(1);
    }
    __syncthreads();
}

template<int LAYER>
__global__ __launch_bounds__(512, 2) void lstm_layer(
    const float* __restrict__ x,      // [512,64,512]
    const float* __restrict__ Wp,     // ws: packed weights
    const float* __restrict__ bih,    // [4,2048]
    const float* __restrict__ bhh,    // [4,2048]
    const float* __restrict__ mx0,    // [2,64,512]
    const float* __restrict__ mx1,    // [2,64,1024]
    const float* __restrict__ mhm,    // [4,64,512]
    float* __restrict__ out0,         // ws: [512,64,1024] layer-0 output
    float* __restrict__ hmT,          // ws: [2][4,512,64] (h*mh)^T dbl-buffered
    unsigned* __restrict__ barbase,   // ws: barrier block
    float* __restrict__ dout)         // [S,B,1024] ++ hn[4,64,512] ++ cn[4,64,512]
{
    constexpr int Kin = LAYER ? 1024 : 512;
    constexpr int NCH = (Kin + HID)/CHK;       // 16 (L0) or 24 (L1)
    constexpr int HCH = Kin/CHK;               // first h chunk: 8 / 16

    __shared__ __align__(16) float At[2*ABUF];  // 34.8 KB (A dbuf; reduce reuse)

    unsigned* bar = barbase + LAYER*1024;

    const int g    = blockIdx.x;
    const int dir  = g >> 7;
    const int wg   = g & 127;
    const int cell = LAYER*2 + dir;
    const int u0   = wg*4;
    const int tid  = threadIdx.x;
    const int lane = tid & 63;
    const int wv   = tid >> 6;                 // wave 0..7

    // compute tile: lane = (bg 0..15) x (cg 0..3); 4 b x 4 c per lane;
    // wave wv owns k-rows wv*8..wv*8+7 of each 64-k chunk.
    const int r0 = (lane & 15)*4;              // batch rows
    const int cg = lane >> 4;                  // col group (4 cols)

    const float* wp = (LAYER == 0)
        ? Wp + (size_t)(cell*128 + wg)*16384
        : Wp + (size_t)PACK_B2 + (size_t)(dir*128 + wg)*24576;
    const float* wpc = wp + cg*4;              // + k*16 per row

    // A staging: x-part (transpose): thread -> (batch sb, 8-k block aks)
    const int sb  = tid & 63;
    const int aks = (tid >> 6)*8;
    // A staging: h-part (already transposed): thread -> (k-row, b-octet)
    const int hkrow = tid >> 3;
    const int hb    = (tid & 7)*8;

    // elementwise (first 256 threads): (batch eb, unit u0+eu)
    const int eb = tid & 63;
    const int eu = tid >> 6;
    float bsum[4] = {0.f, 0.f, 0.f, 0.f};
    float mreg = 0.f;
    float* haddr0 = nullptr;
    size_t sidx = 0;
    if (tid < 256) {
#pragma unroll
        for (int q = 0; q < 4; ++q) {
            const int gc = cell*2048 + q*512 + u0 + eu;
            bsum[q] = bih[gc] + bhh[gc];
        }
        sidx   = ((size_t)(cell*64 + eb))*512 + u0 + eu;
        mreg   = mhm[sidx];
        haddr0 = hmT + ((size_t)(cell*512 + u0 + eu))*64 + eb;
    }
    float creg = 0.0f;

    for (int s = 0; s < SLEN; ++s) {
        const int t = dir ? (SLEN-1-s) : s;
        const float* hrd = hmT + (size_t)(s & 1)*STATE_SZ;
        float* const hwr = haddr0 + (size_t)((s + 1) & 1)*STATE_SZ;

        float acc[4][4];
#pragma unroll
        for (int i = 0; i < 4; ++i)
#pragma unroll
            for (int j = 0; j < 4; ++j) acc[i][j] = 0.0f;

        f32x4 va0, va1, vm0, vm1;
        bool xpart = true;

        auto prefetch = [&](int ch) {
            const int k0 = ch*CHK;
            xpart = (k0 < Kin);
            if (xpart) {
                const float *asrc, *amsk;
                if (LAYER == 0) {
                    asrc = x   + ((size_t)(t*64   + sb))*512  + k0 + aks;
                    amsk = mx0 + ((size_t)(dir*64 + sb))*512  + k0 + aks;
                } else {
                    asrc = out0 + ((size_t)(t*64   + sb))*1024 + k0 + aks;
                    amsk = mx1  + ((size_t)(dir*64 + sb))*1024 + k0 + aks;
                }
                va0 = *(const f32x4*)(asrc);     vm0 = *(const f32x4*)(amsk);
                va1 = *(const f32x4*)(asrc + 4); vm1 = *(const f32x4*)(amsk + 4);
            } else {
                const int kh = k0 - Kin;
                const float* hsrc = hrd + ((size_t)(cell*512 + kh + hkrow))*64 + hb;
                asm volatile("global_load_dwordx4 %0, %1, off sc0 sc1 nt"
                             : "=v"(va0) : "v"(hsrc)     : "memory");
                asm volatile("global_load_dwordx4 %0, %1, off sc0 sc1 nt"
                             : "=v"(va1) : "v"(hsrc + 4) : "memory");
            }
        };

        auto writeb = [&](float* Ab) {
            if (xpart) {
                const f32x4 p0 = va0*vm0, p1 = va1*vm1;
                float* col = Ab + aks*APAD + sb;
                col[0*APAD] = p0.x; col[1*APAD] = p0.y;
                col[2*APAD] = p0.z; col[3*APAD] = p0.w;
                col[4*APAD] = p1.x; col[5*APAD] = p1.y;
                col[6*APAD] = p1.z; col[7*APAD] = p1.w;
            } else {
                asm volatile("s_waitcnt vmcnt(0)" ::: "memory");
                *(f32x4*)(Ab + hkrow*APAD + hb)     = va0;
                *(f32x4*)(Ab + hkrow*APAD + hb + 4) = va1;
            }
        };

        auto compute = [&](const float* Ab, int k0) {
            const float* wr = wpc + (size_t)(k0 + wv*8)*16;
            f32x4 w[8];
#pragma unroll
            for (int kk = 0; kk < 8; ++kk)
                w[kk] = *(const f32x4*)(wr + kk*16);     // dense L2 hit
#pragma unroll
            for (int kk = 0; kk < 8; ++kk) {
                const f32x4 a = *(const f32x4*)(Ab + (wv*8 + kk)*APAD + r0);
#pragma unroll
                for (int i = 0; i < 4; ++i) {
                    acc[i][0] += a[i]*w[kk].x; acc[i][1] += a[i]*w[kk].y;
                    acc[i][2] += a[i]*w[kk].z; acc[i][3] += a[i]*w[kk].w;
                }
            }
        };

        // ---- pipelined K loop: sync -> [wait] -> prefetch(next) -> compute ----
        prefetch(0);
        writeb(At);
        for (int ch = 0; ch < NCH; ++ch) {
            __syncthreads();
            if (ch == HCH - 1 && s > 0)
                bar_wait(bar, (unsigned)s);      // h(s) fabric-visible
            const int p = ch & 1;
            if (ch + 1 < NCH) prefetch(ch + 1);
            compute(At + p*ABUF, ch*CHK);
            if (ch + 1 < NCH) writeb(At + (p^1)*ABUF);
        }
        __syncthreads();                         // all compute done before reuse

        // ---- cross-wave reduce: red[wv][c16][b] (RPAD rows), reuses At ----
        float* red = At;
#pragma unroll
        for (int j = 0; j < 4; ++j) {
            f32x4 v = {acc[0][j], acc[1][j], acc[2][j], acc[3][j]};
            *(f32x4*)(red + (wv*16 + cg*4 + j)*RPAD + r0) = v;
        }
        __syncthreads();

        // ---- elementwise + state update (first 256 threads) ----
        if (tid < 256) {
            float gq[4];
#pragma unroll
            for (int q = 0; q < 4; ++q) {
                const int c = q*4 + eu;
                float v = bsum[q];
#pragma unroll
                for (int w = 0; w < 8; ++w) v += red[(w*16 + c)*RPAD + eb];
                gq[q] = v;
            }
            const float ig = 1.0f/(1.0f + expf(-gq[0]));
            const float fg = 1.0f/(1.0f + expf(-gq[1]));
            const float gg = tanhf(gq[2]);
            const float og = 1.0f/(1.0f + expf(-gq[3]));
            const float cnew = fg*creg + ig*gg;
            const float hnew = og*tanhf(cnew);
            creg = cnew;
            const float hm = hnew * mreg;
            asm volatile("global_store_dword %0, %1, off sc0 sc1 nt"
                         :: "v"(hwr), "v"(hm) : "memory");
            float* obase = LAYER ? dout : out0;
            obase[((size_t)(t*64 + eb))*1024 + dir*512 + u0 + eu] = hnew;
            if (s == SLEN-1) {
                dout[OUT_SEQ + sidx]            = hnew;   // h_n
                dout[OUT_SEQ + STATE_SZ + sidx] = cnew;   // c_n
            }
        }

        if (s + 1 < SLEN) bar_arrive(bar, g);    // non-blocking arrival
    }
}

extern "C" void kernel_launch(void* const* d_in, const int* in_sizes, int n_in,
                              void* d_out, int out_size, void* d_ws, size_t ws_size,
                              hipStream_t stream)
{
    const float* x    = (const float*)d_in[0];
    const float* Wih0 = (const float*)d_in[1];
    const float* Wih1 = (const float*)d_in[2];
    const float* Whh  = (const float*)d_in[3];
    const float* bih  = (const float*)d_in[4];
    const float* bhh  = (const float*)d_in[5];
    const float* mx0  = (const float*)d_in[6];
    const float* mx1  = (const float*)d_in[7];
    const float* mhm  = (const float*)d_in[8];

    float* out  = (float*)d_out;
    float* out0 = (float*)d_ws;                      // [512,64,1024]
    float* hmT  = out0 + OUT_SEQ;                    // [2][4,512,64]
    float* Wp   = hmT + 2*STATE_SZ;                  // packed weights (41.9 MB)
    unsigned* bar = (unsigned*)(Wp + (size_t)PACK_TOTAL);  // 2 x 1024 u32

    pack_w<<<512, 256, 0, stream>>>(Wih0, Wih1, Whh, Wp);
    init_ws<<<136, 256, 0, stream>>>(hmT, bar);
    lstm_layer<0><<<256, 512, 0, stream>>>(x, Wp, bih, bhh,
                                           mx0, mx1, mhm, out0, hmT, bar, out);
    lstm_layer<1><<<256, 512, 0, stream>>>(x, Wp, bih, bhh,
                                           mx0, mx1, mhm, out0, hmT, bar, out);
}